// Round 5
// baseline (54.767 us; speedup 1.0000x reference)
//
#include <hip/hip_runtime.h>

#define QN 32768
#define GN 64
#define BSN 16
#define KM 4
#define GPB 4
#define NTHREADS 1024
#define NWAVES (NTHREADS / 64)
#define NLISTS (GPB * 2)
#define BUFCAP 64
#define INF __builtin_inff()

// a <- lowest-4 of merge(a,b), both ascending-sorted float[4]. 12 f32 minmax.
__device__ __forceinline__ void merge4f(float* a, const float* b) {
    float m0 = fminf(a[0], b[3]);
    float m1 = fminf(a[1], b[2]);
    float m2 = fminf(a[2], b[1]);
    float m3 = fminf(a[3], b[0]);
    float x0 = fminf(m0, m2), x2 = fmaxf(m0, m2);
    float x1 = fminf(m1, m3), x3 = fmaxf(m1, m3);
    a[0] = fminf(x0, x1); a[1] = fmaxf(x0, x1);
    a[2] = fminf(x2, x3); a[3] = fmaxf(x2, x3);
}

// 8 L1 costs for one q (4 gt x {pred, anchor}), exact reference op order:
// ((|dcx|+|dcy|)+|dw|)+|dh|  -- no contractible FMA patterns, bit-stable.
__device__ __forceinline__ void costs8(
    const float* gcx, const float* gcy, const float* gww, const float* ghh,
    float4 p, float4 a, float* c)
{
    float pcx = (p.x + p.z) * 0.5f, pcy = (p.y + p.w) * 0.5f;
    float pw  = p.z - p.x,          ph  = p.w - p.y;
    float acx = (a.x + a.z) * 0.5f, acy = (a.y + a.w) * 0.5f;
    float aw  = a.z - a.x,          ah  = a.w - a.y;
#pragma unroll
    for (int gl = 0; gl < GPB; ++gl) {
        c[gl*2+0] = ((fabsf(pcx - gcx[gl]) + fabsf(pcy - gcy[gl]))
                     + fabsf(pw - gww[gl])) + fabsf(ph - ghh[gl]);
        c[gl*2+1] = ((fabsf(acx - gcx[gl]) + fabsf(acy - gcy[gl]))
                     + fabsf(aw - gww[gl])) + fabsf(ah - ghh[gl]);
    }
}

__global__ __launch_bounds__(NTHREADS) void UniformMatcher_kernel(
    const float4* __restrict__ pred, const float4* __restrict__ anc,
    const float4* __restrict__ gt, int* __restrict__ out)
{
    __shared__ float ws4[NLISTS][NWAVES][KM];          // per-wave top-4 of minima
    __shared__ float Ts[NLISTS];                       // thresholds
    __shared__ int   cnt[NLISTS];
    __shared__ unsigned long long buf[NLISTS][BUFCAP]; // collected (cost,idx) keys

    // XCD swizzle: 2 batches per XCD so the working set fits its private L2.
    int bid = blockIdx.x;
    int xcd = bid & 7;
    int k   = bid >> 3;
    int b   = (xcd << 1) | (k & 1);     // 0..15
    int gc  = k >> 1;                   // 0..15
    int tid = threadIdx.x;

    float gcx[GPB], gcy[GPB], gww[GPB], ghh[GPB];
#pragma unroll
    for (int gl = 0; gl < GPB; ++gl) {
        float4 gb = gt[b * GN + gc * GPB + gl];
        gcx[gl] = (gb.x + gb.z) * 0.5f;
        gcy[gl] = (gb.y + gb.w) * 0.5f;
        gww[gl] = gb.z - gb.x;
        ghh[gl] = gb.w - gb.y;
    }

    const float4* pb = pred + (size_t)b * QN;
    const float4* ab = anc  + (size_t)b * QN;

    // ---- phase A: per-thread running MIN cost per list (1 v_min_f32/entry) ----
    float mn[NLISTS];
#pragma unroll
    for (int l = 0; l < NLISTS; ++l) mn[l] = INF;

    for (int q0 = tid; q0 < QN; q0 += 4 * NTHREADS) {
        float4 p[4], a[4];
#pragma unroll
        for (int u = 0; u < 4; ++u) {
            p[u] = pb[q0 + u * NTHREADS];
            a[u] = ab[q0 + u * NTHREADS];
        }
#pragma unroll
        for (int u = 0; u < 4; ++u) {
            float c[NLISTS];
            costs8(gcx, gcy, gww, ghh, p[u], a[u], c);
#pragma unroll
            for (int l = 0; l < NLISTS; ++l) mn[l] = fminf(mn[l], c[l]);
        }
    }

    // block-level 4th-smallest of the 1024 per-thread minima = threshold T >= v4.
    // (If a thread held >=2 of the true top-4, dropped ones are replaced by
    //  larger values -> T only overestimates; {cost<=T} still covers top-4.)
    float m4[NLISTS][KM];
#pragma unroll
    for (int l = 0; l < NLISTS; ++l) {
        m4[l][0] = mn[l]; m4[l][1] = INF; m4[l][2] = INF; m4[l][3] = INF;
    }
#pragma unroll
    for (int off = 1; off < 64; off <<= 1) {
#pragma unroll
        for (int l = 0; l < NLISTS; ++l) {
            float bb[KM];
#pragma unroll
            for (int s = 0; s < KM; ++s) bb[s] = __shfl_xor(m4[l][s], off, 64);
            merge4f(m4[l], bb);
        }
    }

    int lane = tid & 63, wv = tid >> 6;
    if (lane == 0) {
#pragma unroll
        for (int l = 0; l < NLISTS; ++l)
#pragma unroll
            for (int s = 0; s < KM; ++s) ws4[l][wv][s] = m4[l][s];
    }
    if (tid < NLISTS) cnt[tid] = 0;
    __syncthreads();

    if (tid < NLISTS) {
        float r[KM];
#pragma unroll
        for (int s = 0; s < KM; ++s) r[s] = ws4[tid][0][s];
        for (int w = 1; w < NWAVES; ++w) merge4f(r, ws4[tid][w]);
        Ts[tid] = r[3];
    }
    __syncthreads();

    float T[NLISTS];
#pragma unroll
    for (int l = 0; l < NLISTS; ++l) T[l] = Ts[l];

    // ---- phase B: rescan (L2-hot), collect all entries with cost <= T ----
    for (int q0 = tid; q0 < QN; q0 += 4 * NTHREADS) {
        float4 p[4], a[4];
#pragma unroll
        for (int u = 0; u < 4; ++u) {
            p[u] = pb[q0 + u * NTHREADS];
            a[u] = ab[q0 + u * NTHREADS];
        }
#pragma unroll
        for (int u = 0; u < 4; ++u) {
            float c[NLISTS];
            costs8(gcx, gcy, gww, ghh, p[u], a[u], c);
            bool any = false;
#pragma unroll
            for (int l = 0; l < NLISTS; ++l) any = any || (c[l] <= T[l]);
            if (__any(any)) {              // rare: ~10% of wave-iterations
                int q = q0 + u * NTHREADS;
#pragma unroll
                for (int l = 0; l < NLISTS; ++l) {
                    if (c[l] <= T[l]) {
                        int slot = atomicAdd(&cnt[l], 1) & (BUFCAP - 1);
                        // key = cost_bits * 2^15 + q : lex (cost, idx) order,
                        // lower idx wins ties; q = key & 32767.
                        buf[l][slot] = (((unsigned long long)__float_as_uint(c[l])) << 15)
                                       | (unsigned long long)(unsigned)q;
                    }
                }
            }
        }
    }
    __syncthreads();

    // ---- exact lexicographic top-4 over the few collected keys ----
    if (tid < NLISTS) {
        int l = tid;
        int n = cnt[l]; if (n > BUFCAP) n = BUFCAP;
        unsigned long long r0 = ~0ull, r1 = ~0ull, r2 = ~0ull, r3 = ~0ull;
        for (int i = 0; i < n; ++i) {
            unsigned long long kk = buf[l][i];
            if (kk < r3) {
                r3 = kk;
                unsigned long long t;
                if (r3 < r2) { t = r2; r2 = r3; r3 = t; }
                if (r2 < r1) { t = r1; r1 = r2; r2 = t; }
                if (r1 < r0) { t = r0; r0 = r1; r1 = t; }
            }
        }
        int gl = l >> 1, type = l & 1;
        int g = gc * GPB + gl;
        int base = b * (2 * KM * GN);
        int* out_j = out + BSN * 2 * KM * GN;
        unsigned long long rr[KM] = { r0, r1, r2, r3 };
#pragma unroll
        for (int mm = 0; mm < KM; ++mm) {
            int qi = (int)(rr[mm] & 32767ull);
            // idx_i layout: [b, m, type, g] -> b*512 + m*128 + type*64 + g
            int pos = base + mm * (2 * GN) + type * GN + g;
            out[pos]   = qi;
            out_j[pos] = g;
        }
    }
}

extern "C" void kernel_launch(void* const* d_in, const int* in_sizes, int n_in,
                              void* d_out, int out_size, void* d_ws, size_t ws_size,
                              hipStream_t stream) {
    const float4* pred = (const float4*)d_in[0];
    const float4* anc  = (const float4*)d_in[1];
    const float4* gt   = (const float4*)d_in[2];
    int* out = (int*)d_out;
    dim3 grid(BSN * (GN / GPB));   // 256 blocks, 1 per CU
    UniformMatcher_kernel<<<grid, NTHREADS, 0, stream>>>(pred, anc, gt, out);
}